// Round 11
// baseline (116.908 us; speedup 1.0000x reference)
//
#include <hip/hip_runtime.h>
#include <stdint.h>

typedef __attribute__((ext_vector_type(8))) __bf16 bf16x8;
typedef __attribute__((ext_vector_type(4))) float f32x4;
typedef __attribute__((ext_vector_type(4))) unsigned short u16x4;

typedef __attribute__((address_space(1))) unsigned int as1_uint;
typedef __attribute__((address_space(3))) unsigned int as3_uint;

__device__ __forceinline__ unsigned short f2bf(float f) {
  unsigned int u = __float_as_uint(f);
  u += 0x7fffu + ((u >> 16) & 1u);
  return (unsigned short)(u >> 16);
}

__device__ __forceinline__ void gload_lds16(const void* g, void* l) {
  __builtin_amdgcn_global_load_lds((as1_uint*)(uintptr_t)g, (as3_uint*)(uintptr_t)l,
                                   16, 0, 0);
}

// -------- fp32 -> bf16 elementwise convert, all 4 inputs in ONE dispatch --------
__global__ void cvt_all(const float* __restrict__ x, const float* __restrict__ qp,
                        const float* __restrict__ kp, const float* __restrict__ vp,
                        unsigned short* __restrict__ xb, unsigned short* __restrict__ qpb,
                        unsigned short* __restrict__ kpb, unsigned short* __restrict__ vpb) {
  const int b = blockIdx.x;
  const float* in;
  unsigned short* out;
  int base;
  if (b < 4096)      { in = x;  out = xb;  base = b; }
  else if (b < 8192) { in = qp; out = qpb; base = b - 4096; }
  else if (b < 9216) { in = kp; out = kpb; base = b - 8192; }
  else               { in = vp; out = vpb; base = b - 9216; }
  const int i = base * 256 + threadIdx.x;
  float4 v = ((const float4*)in)[i];
  u16x4 o;
  o[0] = f2bf(v.x); o[1] = f2bf(v.y); o[2] = f2bf(v.z); o[3] = f2bf(v.w);
  ((u16x4*)out)[i] = o;
}

// ------------- fp32 [R][C] -> bf16 [C][R] tiled transpose-convert --------------
__global__ __launch_bounds__(256)
void transpose_cvt(const float* __restrict__ in, unsigned short* __restrict__ out,
                   int R, int C) {
  __shared__ unsigned short t[64][72];
  const int ti = blockIdx.y * 64;
  const int tj = blockIdx.x * 64;
  const int r  = threadIdx.x >> 4;
  const int c4 = (threadIdx.x & 15) * 4;
#pragma unroll
  for (int i = 0; i < 4; ++i) {
    int row = r + i * 16;
    float4 v = *(const float4*)&in[(size_t)(ti + row) * C + tj + c4];
    t[row][c4]     = f2bf(v.x);
    t[row][c4 + 1] = f2bf(v.y);
    t[row][c4 + 2] = f2bf(v.z);
    t[row][c4 + 3] = f2bf(v.w);
  }
  __syncthreads();
#pragma unroll
  for (int i = 0; i < 4; ++i) {
    int orow = r + i * 16;  // column index j of input
    u16x4 o;
    o[0] = t[c4][orow]; o[1] = t[c4 + 1][orow];
    o[2] = t[c4 + 2][orow]; o[3] = t[c4 + 3][orow];
    *(u16x4*)&out[(size_t)(tj + orow) * R + ti + c4] = o;
  }
}

// ---------------- NT GEMM body: C[M][N] = A[M][K] * B[N][K]^T, bf16 MFMA --------
template <int BN, bool OUT_BF16>
__device__ __forceinline__
void gemm_body(const unsigned short* __restrict__ A,
               const unsigned short* __restrict__ B,
               void* __restrict__ Cout, int N, int K, float alpha,
               int bx, int by, unsigned short* lA, unsigned short* lB) {
  constexpr int NF  = BN / 32;   // 16-col fragments per wave
  constexpr int ASZ = 64 * 64;
  constexpr int BSZ = BN * 64;
  const int tid  = threadIdx.x;
  const int lane = tid & 63;
  const int w    = tid >> 6;
  const int wr   = (w >> 1) * 32;
  const int wc   = (w & 1) * (BN / 2);
  const long brow = (long)by * 64;
  const long bcol = (long)bx * BN;
  const int lr = lane & 15;
  const int lq = lane >> 4;

  const int row0 = tid >> 3;
  const int lc0  = (tid & 7) ^ (row0 & 7);

  f32x4 acc[2][NF] = {};

  const unsigned short* gA = A + (brow + row0) * (long)K + lc0 * 8;
  const unsigned short* gB = B + (bcol + row0) * (long)K + lc0 * 8;

#define G_STAGE(buf, k0)                                                          \
  {                                                                               \
    gload_lds16(gA + (k0),           lA + (buf) * ASZ + tid * 8);                 \
    gload_lds16(gA + 32l * K + (k0), lA + (buf) * ASZ + 2048 + tid * 8);          \
    _Pragma("unroll")                                                             \
    for (int g = 0; g < NF; ++g)                                                  \
      gload_lds16(gB + g * 32l * K + (k0), lB + (buf) * BSZ + g * 2048 + tid * 8);\
  }

  G_STAGE(0, 0);
  __syncthreads();

  for (int k0 = 0; k0 < K; k0 += 64) {
    const int cur = (k0 >> 6) & 1;
    if (k0 + 64 < K) G_STAGE(cur ^ 1, k0 + 64);  // prefetch rides through compute
#pragma unroll
    for (int kk = 0; kk < 2; ++kk) {
      const int j = kk * 4 + lq;
      const int ra0 = wr + lr, ra1 = wr + 16 + lr;
      bf16x8 a0 = *(const bf16x8*)&lA[cur * ASZ + ra0 * 64 + ((j ^ (ra0 & 7)) << 3)];
      bf16x8 a1 = *(const bf16x8*)&lA[cur * ASZ + ra1 * 64 + ((j ^ (ra1 & 7)) << 3)];
      bf16x8 b[NF];
#pragma unroll
      for (int n = 0; n < NF; ++n) {
        const int rb = wc + n * 16 + lr;
        b[n] = *(const bf16x8*)&lB[cur * BSZ + rb * 64 + ((j ^ (rb & 7)) << 3)];
      }
#pragma unroll
      for (int n = 0; n < NF; ++n) {
        acc[0][n] = __builtin_amdgcn_mfma_f32_16x16x32_bf16(a0, b[n], acc[0][n], 0, 0, 0);
        acc[1][n] = __builtin_amdgcn_mfma_f32_16x16x32_bf16(a1, b[n], acc[1][n], 0, 0, 0);
      }
    }
    __syncthreads();
  }
#undef G_STAGE

  const int orow = (int)brow + wr + lq * 4;
  const int ocol = (int)bcol + wc + lr;
#pragma unroll
  for (int m = 0; m < 2; ++m)
#pragma unroll
    for (int n = 0; n < NF; ++n)
#pragma unroll
      for (int r = 0; r < 4; ++r) {
        size_t row = (size_t)(orow + m * 16 + r);
        size_t col = (size_t)(ocol + n * 16);
        float v = acc[m][n][r] * alpha;
        if (OUT_BF16)
          ((unsigned short*)Cout)[row * N + col] = f2bf(v);
        else
          ((float*)Cout)[row * N + col] = v;
      }
}

template <int BN, bool OUT_BF16>
__global__ __launch_bounds__(256)
void gemm_nt(const unsigned short* __restrict__ A,
             const unsigned short* __restrict__ B,
             void* __restrict__ Cout, int N, int K, float alpha) {
  __shared__ unsigned short lA[2 * 64 * 64];
  __shared__ unsigned short lB[2 * BN * 64];
  gemm_body<BN, OUT_BF16>(A, B, Cout, N, K, alpha, blockIdx.x, blockIdx.y, lA, lB);
}

// Fused Q+K+V projections, one dispatch, flat 768-block decode (all BN=128):
//   [0,512)   Q = xb @ qpb^T (alpha=log2e/8), 16x * 32y
//   [512,640) K = xb @ kpb^T,                  4x * 32y
//   [640,768) Vt = vpb @ xb^T,                16x *  8y
__global__ __launch_bounds__(256)
void gemm_proj(const unsigned short* __restrict__ xb,
               const unsigned short* __restrict__ qpb,
               const unsigned short* __restrict__ kpb,
               const unsigned short* __restrict__ vpb,
               unsigned short* __restrict__ Qb, unsigned short* __restrict__ Kbf,
               unsigned short* __restrict__ Vtb) {
  __shared__ unsigned short lA[2 * 64 * 64];
  __shared__ unsigned short lB[2 * 128 * 64];
  const int bid = blockIdx.x;
  const unsigned short *A, *B;
  unsigned short* C;
  int N, bx, by;
  float alpha;
  if (bid < 512) {
    A = xb;  B = qpb; C = Qb;  N = 2048; alpha = 0.125f * 1.44269504088896f;
    bx = bid & 15; by = bid >> 4;
  } else if (bid < 640) {
    int b = bid - 512;
    A = xb;  B = kpb; C = Kbf; N = 512;  alpha = 1.0f;
    bx = b & 3; by = b >> 2;
  } else {
    int b = bid - 640;
    A = vpb; B = xb;  C = Vtb; N = 2048; alpha = 1.0f;
    bx = b & 15; by = b >> 4;
  }
  gemm_body<128, true>(A, B, C, N, 2048, alpha, bx, by, lA, lB);
}

// ---------------- causal GQA flash attention ----------------
// Grid (32,16): x = head (pins all blocks of a head to XCD h%8), y = q-tile pair.
// 3-deep LDS pipeline, counted vmcnt(4) + raw s_barrier per tile (T3+T4):
// prefetch of tile t+2 stays in flight across the barrier; only tile t+1's 4
// stage-loads are waited. Tail iterations drain with vmcnt(0). All barrier
// conditions are block-uniform (depend on t, nt only).
__global__ __launch_bounds__(256)
void attn64(const unsigned short* __restrict__ Q,
            const unsigned short* __restrict__ Kb,
            const unsigned short* __restrict__ Vt,
            unsigned short* __restrict__ ctx) {
  constexpr int T = 2048, DQ = 2048, DKV = 512, DH = 64;
  const int h    = blockIdx.x;
  const int hkv  = h >> 2;
  const int tid  = threadIdx.x;
  const int lane = tid & 63;
  const int w    = tid >> 6;
  const int lr   = lane & 15;
  const int lq   = lane >> 4;   // 0..3
  const int lk   = lq * 8;
  const int sw   = lr & 7;      // row-derived swizzle key for fragment reads

  __shared__ unsigned short lK[3][64 * 64];
  __shared__ unsigned short lV[3][64 * 64];
  __shared__ unsigned short P[4][16][72];   // 144B row stride: 16B-aligned b128 reads

  const int row0 = tid >> 3;
  const int lc0  = (tid & 7) ^ (row0 & 7);

  // ones B-fragment for the row-sum MFMA: out-col 0 (lr==0 lanes) = 1.0 over all k
  bf16x8 ones_frag;
#pragma unroll
  for (int i = 0; i < 8; ++i) ones_frag[i] = (lr == 0) ? (__bf16)1.0f : (__bf16)0.0f;

#define STAGE_KV(bufidx, kv0)                                                        \
  {                                                                                  \
    gload_lds16(Kb + (size_t)((kv0) + row0) * DKV + hkv * DH + lc0 * 8,              \
                &lK[bufidx][tid * 8]);                                               \
    gload_lds16(Kb + (size_t)((kv0) + row0 + 32) * DKV + hkv * DH + lc0 * 8,         \
                &lK[bufidx][2048 + tid * 8]);                                        \
    gload_lds16(Vt + (size_t)(hkv * DH + row0) * T + (kv0) + lc0 * 8,                \
                &lV[bufidx][tid * 8]);                                               \
    gload_lds16(Vt + (size_t)(hkv * DH + row0 + 32) * T + (kv0) + lc0 * 8,           \
                &lV[bufidx][2048 + tid * 8]);                                        \
  }

#pragma unroll 1
  for (int pass = 0; pass < 2; ++pass) {
    const int qi  = pass == 0 ? (int)blockIdx.y : 31 - (int)blockIdx.y;
    const int q0b = qi * 64;
    const int qw  = q0b + w * 16;

    bf16x8 qf0 = *(const bf16x8*)&Q[(size_t)(qw + lr) * DQ + h * DH + lk];
    bf16x8 qf1 = *(const bf16x8*)&Q[(size_t)(qw + lr) * DQ + h * DH + 32 + lk];

    f32x4 oacc[4] = {};
    f32x4 lacc = {};
    float mr[4];
#pragma unroll
    for (int r = 0; r < 4; ++r) mr[r] = -3.0e38f;

    const int nt = qi + 1;
    // prologue: fill up to 2 buffers, wait only for buf0
    STAGE_KV(0, 0);
    if (nt > 1) {
      STAGE_KV(1, 64);
      asm volatile("s_waitcnt vmcnt(4)" ::: "memory");
    } else {
      asm volatile("s_waitcnt vmcnt(0)" ::: "memory");
    }
    __builtin_amdgcn_sched_barrier(0);
    __builtin_amdgcn_s_barrier();

    for (int t = 0; t < nt; ++t) {
      const int kv0 = t * 64;
      const int cur = t % 3;
      const bool more = (t + 2 < nt);
      if (more) STAGE_KV((t + 2) % 3, kv0 + 128);  // 2-ahead prefetch

      // ---- QK^T from LDS (swizzled reads); logits in log2 domain ----
      f32x4 s[4];
      __builtin_amdgcn_s_setprio(1);
#pragma unroll
      for (int n = 0; n < 4; ++n) {
        const int krow = n * 16 + lr;
        bf16x8 kf0 = *(const bf16x8*)&lK[cur][krow * 64 + ((lq ^ sw) << 3)];
        bf16x8 kf1 = *(const bf16x8*)&lK[cur][krow * 64 + (((4 + lq) ^ sw) << 3)];
        f32x4 acc = {};
        acc = __builtin_amdgcn_mfma_f32_16x16x32_bf16(qf0, kf0, acc, 0, 0, 0);
        acc = __builtin_amdgcn_mfma_f32_16x16x32_bf16(qf1, kf1, acc, 0, 0, 0);
        s[n] = acc;
      }
      __builtin_amdgcn_s_setprio(0);

      // ---- causal mask: only the diagonal tile needs it ----
      if (t == qi) {
        const int qr0 = qw + (lq << 2);
#pragma unroll
        for (int n = 0; n < 4; ++n) {
          int kc = kv0 + n * 16 + lr;
#pragma unroll
          for (int r = 0; r < 4; ++r)
            if (kc > qr0 + r) s[n][r] = -3.0e38f;
        }
      }

      // ---- online softmax with defer-max (THR = 8 log2-units) ----
      float lml[4];
#pragma unroll
      for (int r = 0; r < 4; ++r)
        lml[r] = fmaxf(fmaxf(s[0][r], s[1][r]), fmaxf(s[2][r], s[3][r]));
      const bool defer = __all((lml[0] <= mr[0] + 8.f) & (lml[1] <= mr[1] + 8.f) &
                               (lml[2] <= mr[2] + 8.f) & (lml[3] <= mr[3] + 8.f));
      if (!defer) {
#pragma unroll
        for (int r = 0; r < 4; ++r) {
          float ml = lml[r];
          ml = fmaxf(ml, __shfl_xor(ml, 1));
          ml = fmaxf(ml, __shfl_xor(ml, 2));
          ml = fmaxf(ml, __shfl_xor(ml, 4));
          ml = fmaxf(ml, __shfl_xor(ml, 8));
          float mnew = fmaxf(mr[r], ml);
          float sc   = __builtin_amdgcn_exp2f(mr[r] - mnew);
          mr[r] = mnew;
          lacc[r] *= sc;
          oacc[0][r] *= sc; oacc[1][r] *= sc;
          oacc[2][r] *= sc; oacc[3][r] *= sc;
        }
      }

      // ---- P = exp2(s - mr) (bounded by 2^8 under defer) ----
#pragma unroll
      for (int n = 0; n < 4; ++n)
#pragma unroll
        for (int r = 0; r < 4; ++r)
          s[n][r] = __builtin_amdgcn_exp2f(s[n][r] - mr[r]);

      // ---- P (C-layout) -> LDS, truncating bf16 (P>=0; error cancels num/denom) ----
#pragma unroll
      for (int n = 0; n < 4; ++n)
#pragma unroll
        for (int r = 0; r < 4; ++r)
          P[w][(lq << 2) + r][n * 16 + lr] =
              (unsigned short)(__float_as_uint(s[n][r]) >> 16);
      asm volatile("s_waitcnt lgkmcnt(0)" ::: "memory");
      __builtin_amdgcn_sched_barrier(0);  // rule #18: keep PV reads below the waitcnt

      // ---- PV + row-sum (ones-MFMA) from LDS (swizzled V reads) ----
      __builtin_amdgcn_s_setprio(1);
#pragma unroll
      for (int ks = 0; ks < 2; ++ks) {
        bf16x8 pf = *(const bf16x8*)&P[w][lr][ks * 32 + lk];
        lacc = __builtin_amdgcn_mfma_f32_16x16x32_bf16(pf, ones_frag, lacc, 0, 0, 0);
#pragma unroll
        for (int n = 0; n < 4; ++n) {
          const int vrow = n * 16 + lr;
          bf16x8 vf = *(const bf16x8*)&lV[cur][vrow * 64 + (((ks * 4 + lq) ^ sw) << 3)];
          oacc[n] = __builtin_amdgcn_mfma_f32_16x16x32_bf16(pf, vf, oacc[n], 0, 0, 0);
        }
      }
      __builtin_amdgcn_s_setprio(0);

      // ---- counted-vmcnt barrier: wait tile t+1's 4 loads; t+2's stay in flight ----
      if (more) asm volatile("s_waitcnt vmcnt(4)" ::: "memory");
      else      asm volatile("s_waitcnt vmcnt(0)" ::: "memory");
      __builtin_amdgcn_sched_barrier(0);
      __builtin_amdgcn_s_barrier();
    }

    float inv[4];
#pragma unroll
    for (int r = 0; r < 4; ++r) {
      float l = __shfl(lacc[r], lane & 48);  // col 0 of own row-group (lr==0 lane)
      inv[r] = 1.f / l;
    }
#pragma unroll
    for (int n = 0; n < 4; ++n)
#pragma unroll
      for (int r = 0; r < 4; ++r) {
        int qrow = qw + (lq << 2) + r;
        ctx[(size_t)qrow * DQ + h * DH + n * 16 + lr] = f2bf(oacc[n][r] * inv[r]);
      }
  }
#undef STAGE_KV
}

extern "C" void kernel_launch(void* const* d_in, const int* in_sizes, int n_in,
                              void* d_out, int out_size, void* d_ws, size_t ws_size,
                              hipStream_t stream) {
  const float* x  = (const float*)d_in[0];
  const float* qp = (const float*)d_in[1];
  const float* kp = (const float*)d_in[2];
  const float* vp = (const float*)d_in[3];
  const float* op = (const float*)d_in[4];

  char* ws = (char*)d_ws;
  const size_t MB = 1024 * 1024;
  unsigned short* xb   = (unsigned short*)(ws + 0 * MB);   // [2048][2048]
  unsigned short* qpb  = (unsigned short*)(ws + 8 * MB);   // [2048][2048]
  unsigned short* kpb  = (unsigned short*)(ws + 16 * MB);  // [512][2048]
  unsigned short* vpb  = (unsigned short*)(ws + 18 * MB);  // [512][2048]
  unsigned short* opT  = (unsigned short*)(ws + 20 * MB);  // [2048][2048] = o_proj^T
  unsigned short* Qb   = (unsigned short*)(ws + 28 * MB);  // [2048][2048]
  unsigned short* Kbf  = (unsigned short*)(ws + 36 * MB);  // [2048][512]
  unsigned short* Vtb  = (unsigned short*)(ws + 38 * MB);  // [512][2048]
  unsigned short* ctxb = (unsigned short*)(ws + 40 * MB);  // [2048][2048]

  // fp32 -> bf16, single dispatch for all four inputs
  cvt_all<<<10240, 256, 0, stream>>>(x, qp, kp, vp, xb, qpb, kpb, vpb);
  transpose_cvt<<<dim3(32, 32), 256, 0, stream>>>(op, opT, 2048, 2048);

  // Fused Q+K+V projections (Q scaled by log2(e)/8 -> log2-domain logits)
  gemm_proj<<<768, 256, 0, stream>>>(xb, qpb, kpb, vpb, Qb, Kbf, Vtb);

  // causal GQA attention (x = head -> XCD-pinned K/V; y = balanced q-tile pair)
  attn64<<<dim3(32, 16), 256, 0, stream>>>(Qb, Kbf, Vtb, ctxb);

  // out = ctx @ o_proj  (via opT, NT form), fp32 epilogue to d_out
  gemm_nt<128, false><<<dim3(16, 32), 256, 0, stream>>>(ctxb, opT, d_out, 2048, 2048, 1.0f);
}

// Round 12
// 116.807 us; speedup vs baseline: 1.0009x; 1.0009x over previous
//
#include <hip/hip_runtime.h>
#include <stdint.h>

typedef __attribute__((ext_vector_type(8))) __bf16 bf16x8;
typedef __attribute__((ext_vector_type(4))) float f32x4;
typedef __attribute__((ext_vector_type(4))) unsigned short u16x4;

typedef __attribute__((address_space(1))) unsigned int as1_uint;
typedef __attribute__((address_space(3))) unsigned int as3_uint;

__device__ __forceinline__ unsigned short f2bf(float f) {
  unsigned int u = __float_as_uint(f);
  u += 0x7fffu + ((u >> 16) & 1u);
  return (unsigned short)(u >> 16);
}

__device__ __forceinline__ void gload_lds16(const void* g, void* l) {
  __builtin_amdgcn_global_load_lds((as1_uint*)(uintptr_t)g, (as3_uint*)(uintptr_t)l,
                                   16, 0, 0);
}

// -------- fp32 -> bf16 elementwise convert, all 4 inputs in ONE dispatch --------
__global__ void cvt_all(const float* __restrict__ x, const float* __restrict__ qp,
                        const float* __restrict__ kp, const float* __restrict__ vp,
                        unsigned short* __restrict__ xb, unsigned short* __restrict__ qpb,
                        unsigned short* __restrict__ kpb, unsigned short* __restrict__ vpb) {
  const int b = blockIdx.x;
  const float* in;
  unsigned short* out;
  int base;
  if (b < 4096)      { in = x;  out = xb;  base = b; }
  else if (b < 8192) { in = qp; out = qpb; base = b - 4096; }
  else if (b < 9216) { in = kp; out = kpb; base = b - 8192; }
  else               { in = vp; out = vpb; base = b - 9216; }
  const int i = base * 256 + threadIdx.x;
  float4 v = ((const float4*)in)[i];
  u16x4 o;
  o[0] = f2bf(v.x); o[1] = f2bf(v.y); o[2] = f2bf(v.z); o[3] = f2bf(v.w);
  ((u16x4*)out)[i] = o;
}

// ------------- fp32 [R][C] -> bf16 [C][R] tiled transpose-convert --------------
__global__ __launch_bounds__(256)
void transpose_cvt(const float* __restrict__ in, unsigned short* __restrict__ out,
                   int R, int C) {
  __shared__ unsigned short t[64][72];
  const int ti = blockIdx.y * 64;
  const int tj = blockIdx.x * 64;
  const int r  = threadIdx.x >> 4;
  const int c4 = (threadIdx.x & 15) * 4;
#pragma unroll
  for (int i = 0; i < 4; ++i) {
    int row = r + i * 16;
    float4 v = *(const float4*)&in[(size_t)(ti + row) * C + tj + c4];
    t[row][c4]     = f2bf(v.x);
    t[row][c4 + 1] = f2bf(v.y);
    t[row][c4 + 2] = f2bf(v.z);
    t[row][c4 + 3] = f2bf(v.w);
  }
  __syncthreads();
#pragma unroll
  for (int i = 0; i < 4; ++i) {
    int orow = r + i * 16;  // column index j of input
    u16x4 o;
    o[0] = t[c4][orow]; o[1] = t[c4 + 1][orow];
    o[2] = t[c4 + 2][orow]; o[3] = t[c4 + 3][orow];
    *(u16x4*)&out[(size_t)(tj + orow) * R + ti + c4] = o;
  }
}

// ---------------- NT GEMM body: C[M][N] = A[M][K] * B[N][K]^T, bf16 MFMA --------
template <int BN, bool OUT_BF16>
__device__ __forceinline__
void gemm_body(const unsigned short* __restrict__ A,
               const unsigned short* __restrict__ B,
               void* __restrict__ Cout, int N, int K, float alpha,
               int bx, int by, unsigned short* lA, unsigned short* lB) {
  constexpr int NF  = BN / 32;   // 16-col fragments per wave
  constexpr int ASZ = 64 * 64;
  constexpr int BSZ = BN * 64;
  const int tid  = threadIdx.x;
  const int lane = tid & 63;
  const int w    = tid >> 6;
  const int wr   = (w >> 1) * 32;
  const int wc   = (w & 1) * (BN / 2);
  const long brow = (long)by * 64;
  const long bcol = (long)bx * BN;
  const int lr = lane & 15;
  const int lq = lane >> 4;

  const int row0 = tid >> 3;
  const int lc0  = (tid & 7) ^ (row0 & 7);

  f32x4 acc[2][NF] = {};

  const unsigned short* gA = A + (brow + row0) * (long)K + lc0 * 8;
  const unsigned short* gB = B + (bcol + row0) * (long)K + lc0 * 8;

#define G_STAGE(buf, k0)                                                          \
  {                                                                               \
    gload_lds16(gA + (k0),           lA + (buf) * ASZ + tid * 8);                 \
    gload_lds16(gA + 32l * K + (k0), lA + (buf) * ASZ + 2048 + tid * 8);          \
    _Pragma("unroll")                                                             \
    for (int g = 0; g < NF; ++g)                                                  \
      gload_lds16(gB + g * 32l * K + (k0), lB + (buf) * BSZ + g * 2048 + tid * 8);\
  }

  G_STAGE(0, 0);
  __syncthreads();

  for (int k0 = 0; k0 < K; k0 += 64) {
    const int cur = (k0 >> 6) & 1;
    if (k0 + 64 < K) G_STAGE(cur ^ 1, k0 + 64);  // prefetch rides through compute
#pragma unroll
    for (int kk = 0; kk < 2; ++kk) {
      const int j = kk * 4 + lq;
      const int ra0 = wr + lr, ra1 = wr + 16 + lr;
      bf16x8 a0 = *(const bf16x8*)&lA[cur * ASZ + ra0 * 64 + ((j ^ (ra0 & 7)) << 3)];
      bf16x8 a1 = *(const bf16x8*)&lA[cur * ASZ + ra1 * 64 + ((j ^ (ra1 & 7)) << 3)];
      bf16x8 b[NF];
#pragma unroll
      for (int n = 0; n < NF; ++n) {
        const int rb = wc + n * 16 + lr;
        b[n] = *(const bf16x8*)&lB[cur * BSZ + rb * 64 + ((j ^ (rb & 7)) << 3)];
      }
#pragma unroll
      for (int n = 0; n < NF; ++n) {
        acc[0][n] = __builtin_amdgcn_mfma_f32_16x16x32_bf16(a0, b[n], acc[0][n], 0, 0, 0);
        acc[1][n] = __builtin_amdgcn_mfma_f32_16x16x32_bf16(a1, b[n], acc[1][n], 0, 0, 0);
      }
    }
    __syncthreads();
  }
#undef G_STAGE

  const int orow = (int)brow + wr + lq * 4;
  const int ocol = (int)bcol + wc + lr;
#pragma unroll
  for (int m = 0; m < 2; ++m)
#pragma unroll
    for (int n = 0; n < NF; ++n)
#pragma unroll
      for (int r = 0; r < 4; ++r) {
        size_t row = (size_t)(orow + m * 16 + r);
        size_t col = (size_t)(ocol + n * 16);
        float v = acc[m][n][r] * alpha;
        if (OUT_BF16)
          ((unsigned short*)Cout)[row * N + col] = f2bf(v);
        else
          ((float*)Cout)[row * N + col] = v;
      }
}

template <int BN, bool OUT_BF16>
__global__ __launch_bounds__(256)
void gemm_nt(const unsigned short* __restrict__ A,
             const unsigned short* __restrict__ B,
             void* __restrict__ Cout, int N, int K, float alpha) {
  __shared__ unsigned short lA[2 * 64 * 64];
  __shared__ unsigned short lB[2 * BN * 64];
  gemm_body<BN, OUT_BF16>(A, B, Cout, N, K, alpha, blockIdx.x, blockIdx.y, lA, lB);
}

// Fused Q+K+V projections, one dispatch, flat 768-block decode (all BN=128):
//   [0,512)   Q = xb @ qpb^T (alpha=log2e/8), 16x * 32y
//   [512,640) K = xb @ kpb^T,                  4x * 32y
//   [640,768) Vt = vpb @ xb^T,                16x *  8y
__global__ __launch_bounds__(256)
void gemm_proj(const unsigned short* __restrict__ xb,
               const unsigned short* __restrict__ qpb,
               const unsigned short* __restrict__ kpb,
               const unsigned short* __restrict__ vpb,
               unsigned short* __restrict__ Qb, unsigned short* __restrict__ Kbf,
               unsigned short* __restrict__ Vtb) {
  __shared__ unsigned short lA[2 * 64 * 64];
  __shared__ unsigned short lB[2 * 128 * 64];
  const int bid = blockIdx.x;
  const unsigned short *A, *B;
  unsigned short* C;
  int N, bx, by;
  float alpha;
  if (bid < 512) {
    A = xb;  B = qpb; C = Qb;  N = 2048; alpha = 0.125f * 1.44269504088896f;
    bx = bid & 15; by = bid >> 4;
  } else if (bid < 640) {
    int b = bid - 512;
    A = xb;  B = kpb; C = Kbf; N = 512;  alpha = 1.0f;
    bx = b & 3; by = b >> 2;
  } else {
    int b = bid - 640;
    A = vpb; B = xb;  C = Vtb; N = 2048; alpha = 1.0f;
    bx = b & 15; by = b >> 4;
  }
  gemm_body<128, true>(A, B, C, N, 2048, alpha, bx, by, lA, lB);
}

// ---------------- causal GQA flash attention ----------------
// Grid (32,16): x = head (pins all blocks of a head to XCD h%8), y = q-tile pair.
// 3-deep LDS pipeline, counted vmcnt(4) + raw s_barrier per tile (T3+T4):
// prefetch of tile t+2 stays in flight across the barrier; only tile t+1's 4
// stage-loads are waited. Tail iterations drain with vmcnt(0). All barrier
// conditions are block-uniform (depend on t, nt only).
__global__ __launch_bounds__(256)
void attn64(const unsigned short* __restrict__ Q,
            const unsigned short* __restrict__ Kb,
            const unsigned short* __restrict__ Vt,
            unsigned short* __restrict__ ctx) {
  constexpr int T = 2048, DQ = 2048, DKV = 512, DH = 64;
  const int h    = blockIdx.x;
  const int hkv  = h >> 2;
  const int tid  = threadIdx.x;
  const int lane = tid & 63;
  const int w    = tid >> 6;
  const int lr   = lane & 15;
  const int lq   = lane >> 4;   // 0..3
  const int lk   = lq * 8;
  const int sw   = lr & 7;      // row-derived swizzle key for fragment reads

  __shared__ unsigned short lK[3][64 * 64];
  __shared__ unsigned short lV[3][64 * 64];
  __shared__ unsigned short P[4][16][72];   // 144B row stride: 16B-aligned b128 reads

  const int row0 = tid >> 3;
  const int lc0  = (tid & 7) ^ (row0 & 7);

  // ones B-fragment for the row-sum MFMA: out-col 0 (lr==0 lanes) = 1.0 over all k
  bf16x8 ones_frag;
#pragma unroll
  for (int i = 0; i < 8; ++i) ones_frag[i] = (lr == 0) ? (__bf16)1.0f : (__bf16)0.0f;

#define STAGE_KV(bufidx, kv0)                                                        \
  {                                                                                  \
    gload_lds16(Kb + (size_t)((kv0) + row0) * DKV + hkv * DH + lc0 * 8,              \
                &lK[bufidx][tid * 8]);                                               \
    gload_lds16(Kb + (size_t)((kv0) + row0 + 32) * DKV + hkv * DH + lc0 * 8,         \
                &lK[bufidx][2048 + tid * 8]);                                        \
    gload_lds16(Vt + (size_t)(hkv * DH + row0) * T + (kv0) + lc0 * 8,                \
                &lV[bufidx][tid * 8]);                                               \
    gload_lds16(Vt + (size_t)(hkv * DH + row0 + 32) * T + (kv0) + lc0 * 8,           \
                &lV[bufidx][2048 + tid * 8]);                                        \
  }

#pragma unroll 1
  for (int pass = 0; pass < 2; ++pass) {
    const int qi  = pass == 0 ? (int)blockIdx.y : 31 - (int)blockIdx.y;
    const int q0b = qi * 64;
    const int qw  = q0b + w * 16;

    bf16x8 qf0 = *(const bf16x8*)&Q[(size_t)(qw + lr) * DQ + h * DH + lk];
    bf16x8 qf1 = *(const bf16x8*)&Q[(size_t)(qw + lr) * DQ + h * DH + 32 + lk];

    f32x4 oacc[4] = {};
    f32x4 lacc = {};
    float mr[4];
#pragma unroll
    for (int r = 0; r < 4; ++r) mr[r] = -3.0e38f;

    const int nt = qi + 1;
    // prologue: fill up to 2 buffers, wait only for buf0
    STAGE_KV(0, 0);
    if (nt > 1) {
      STAGE_KV(1, 64);
      asm volatile("s_waitcnt vmcnt(4)" ::: "memory");
    } else {
      asm volatile("s_waitcnt vmcnt(0)" ::: "memory");
    }
    __builtin_amdgcn_sched_barrier(0);
    __builtin_amdgcn_s_barrier();

    for (int t = 0; t < nt; ++t) {
      const int kv0 = t * 64;
      const int cur = t % 3;
      const bool more = (t + 2 < nt);
      if (more) STAGE_KV((t + 2) % 3, kv0 + 128);  // 2-ahead prefetch

      // ---- QK^T from LDS (swizzled reads); logits in log2 domain ----
      f32x4 s[4];
      __builtin_amdgcn_s_setprio(1);
#pragma unroll
      for (int n = 0; n < 4; ++n) {
        const int krow = n * 16 + lr;
        bf16x8 kf0 = *(const bf16x8*)&lK[cur][krow * 64 + ((lq ^ sw) << 3)];
        bf16x8 kf1 = *(const bf16x8*)&lK[cur][krow * 64 + (((4 + lq) ^ sw) << 3)];
        f32x4 acc = {};
        acc = __builtin_amdgcn_mfma_f32_16x16x32_bf16(qf0, kf0, acc, 0, 0, 0);
        acc = __builtin_amdgcn_mfma_f32_16x16x32_bf16(qf1, kf1, acc, 0, 0, 0);
        s[n] = acc;
      }
      __builtin_amdgcn_s_setprio(0);

      // ---- causal mask: only the diagonal tile needs it ----
      if (t == qi) {
        const int qr0 = qw + (lq << 2);
#pragma unroll
        for (int n = 0; n < 4; ++n) {
          int kc = kv0 + n * 16 + lr;
#pragma unroll
          for (int r = 0; r < 4; ++r)
            if (kc > qr0 + r) s[n][r] = -3.0e38f;
        }
      }

      // ---- online softmax with defer-max (THR = 8 log2-units) ----
      float lml[4];
#pragma unroll
      for (int r = 0; r < 4; ++r)
        lml[r] = fmaxf(fmaxf(s[0][r], s[1][r]), fmaxf(s[2][r], s[3][r]));
      const bool defer = __all((lml[0] <= mr[0] + 8.f) & (lml[1] <= mr[1] + 8.f) &
                               (lml[2] <= mr[2] + 8.f) & (lml[3] <= mr[3] + 8.f));
      if (!defer) {
#pragma unroll
        for (int r = 0; r < 4; ++r) {
          float ml = lml[r];
          ml = fmaxf(ml, __shfl_xor(ml, 1));
          ml = fmaxf(ml, __shfl_xor(ml, 2));
          ml = fmaxf(ml, __shfl_xor(ml, 4));
          ml = fmaxf(ml, __shfl_xor(ml, 8));
          float mnew = fmaxf(mr[r], ml);
          float sc   = __builtin_amdgcn_exp2f(mr[r] - mnew);
          mr[r] = mnew;
          lacc[r] *= sc;
          oacc[0][r] *= sc; oacc[1][r] *= sc;
          oacc[2][r] *= sc; oacc[3][r] *= sc;
        }
      }

      // ---- P = exp2(s - mr) (bounded by 2^8 under defer) ----
#pragma unroll
      for (int n = 0; n < 4; ++n)
#pragma unroll
        for (int r = 0; r < 4; ++r)
          s[n][r] = __builtin_amdgcn_exp2f(s[n][r] - mr[r]);

      // ---- P (C-layout) -> LDS, truncating bf16 (P>=0; error cancels num/denom) ----
#pragma unroll
      for (int n = 0; n < 4; ++n)
#pragma unroll
        for (int r = 0; r < 4; ++r)
          P[w][(lq << 2) + r][n * 16 + lr] =
              (unsigned short)(__float_as_uint(s[n][r]) >> 16);
      asm volatile("s_waitcnt lgkmcnt(0)" ::: "memory");
      __builtin_amdgcn_sched_barrier(0);  // rule #18: keep PV reads below the waitcnt

      // ---- PV + row-sum (ones-MFMA) from LDS (swizzled V reads) ----
      __builtin_amdgcn_s_setprio(1);
#pragma unroll
      for (int ks = 0; ks < 2; ++ks) {
        bf16x8 pf = *(const bf16x8*)&P[w][lr][ks * 32 + lk];
        lacc = __builtin_amdgcn_mfma_f32_16x16x32_bf16(pf, ones_frag, lacc, 0, 0, 0);
#pragma unroll
        for (int n = 0; n < 4; ++n) {
          const int vrow = n * 16 + lr;
          bf16x8 vf = *(const bf16x8*)&lV[cur][vrow * 64 + (((ks * 4 + lq) ^ sw) << 3)];
          oacc[n] = __builtin_amdgcn_mfma_f32_16x16x32_bf16(pf, vf, oacc[n], 0, 0, 0);
        }
      }
      __builtin_amdgcn_s_setprio(0);

      // ---- counted-vmcnt barrier: wait tile t+1's 4 loads; t+2's stay in flight ----
      if (more) asm volatile("s_waitcnt vmcnt(4)" ::: "memory");
      else      asm volatile("s_waitcnt vmcnt(0)" ::: "memory");
      __builtin_amdgcn_sched_barrier(0);
      __builtin_amdgcn_s_barrier();
    }

    float inv[4];
#pragma unroll
    for (int r = 0; r < 4; ++r) {
      float l = __shfl(lacc[r], lane & 48);  // col 0 of own row-group (lr==0 lane)
      inv[r] = 1.f / l;
    }
#pragma unroll
    for (int n = 0; n < 4; ++n)
#pragma unroll
      for (int r = 0; r < 4; ++r) {
        int qrow = qw + (lq << 2) + r;
        ctx[(size_t)qrow * DQ + h * DH + n * 16 + lr] = f2bf(oacc[n][r] * inv[r]);
      }
  }
#undef STAGE_KV
}

extern "C" void kernel_launch(void* const* d_in, const int* in_sizes, int n_in,
                              void* d_out, int out_size, void* d_ws, size_t ws_size,
                              hipStream_t stream) {
  const float* x  = (const float*)d_in[0];
  const float* qp = (const float*)d_in[1];
  const float* kp = (const float*)d_in[2];
  const float* vp = (const float*)d_in[3];
  const float* op = (const float*)d_in[4];

  char* ws = (char*)d_ws;
  const size_t MB = 1024 * 1024;
  unsigned short* xb   = (unsigned short*)(ws + 0 * MB);   // [2048][2048]
  unsigned short* qpb  = (unsigned short*)(ws + 8 * MB);   // [2048][2048]
  unsigned short* kpb  = (unsigned short*)(ws + 16 * MB);  // [512][2048]
  unsigned short* vpb  = (unsigned short*)(ws + 18 * MB);  // [512][2048]
  unsigned short* opT  = (unsigned short*)(ws + 20 * MB);  // [2048][2048] = o_proj^T
  unsigned short* Qb   = (unsigned short*)(ws + 28 * MB);  // [2048][2048]
  unsigned short* Kbf  = (unsigned short*)(ws + 36 * MB);  // [2048][512]
  unsigned short* Vtb  = (unsigned short*)(ws + 38 * MB);  // [512][2048]
  unsigned short* ctxb = (unsigned short*)(ws + 40 * MB);  // [2048][2048]

  // fp32 -> bf16, single dispatch for all four inputs
  cvt_all<<<10240, 256, 0, stream>>>(x, qp, kp, vp, xb, qpb, kpb, vpb);
  transpose_cvt<<<dim3(32, 32), 256, 0, stream>>>(op, opT, 2048, 2048);

  // Fused Q+K+V projections (Q scaled by log2(e)/8 -> log2-domain logits)
  gemm_proj<<<768, 256, 0, stream>>>(xb, qpb, kpb, vpb, Qb, Kbf, Vtb);

  // causal GQA attention (x = head -> XCD-pinned K/V; y = balanced q-tile pair)
  attn64<<<dim3(32, 16), 256, 0, stream>>>(Qb, Kbf, Vtb, ctxb);

  // out = ctx @ o_proj  (via opT, NT form), fp32 epilogue to d_out
  gemm_nt<128, false><<<dim3(16, 32), 256, 0, stream>>>(ctxb, opT, d_out, 2048, 2048, 1.0f);
}

// Round 13
// 113.840 us; speedup vs baseline: 1.0270x; 1.0261x over previous
//
#include <hip/hip_runtime.h>
#include <stdint.h>

typedef __attribute__((ext_vector_type(8))) __bf16 bf16x8;
typedef __attribute__((ext_vector_type(4))) float f32x4;
typedef __attribute__((ext_vector_type(4))) unsigned short u16x4;

typedef __attribute__((address_space(1))) unsigned int as1_uint;
typedef __attribute__((address_space(3))) unsigned int as3_uint;

__device__ __forceinline__ unsigned short f2bf(float f) {
  unsigned int u = __float_as_uint(f);
  u += 0x7fffu + ((u >> 16) & 1u);
  return (unsigned short)(u >> 16);
}

__device__ __forceinline__ void gload_lds16(const void* g, void* l) {
  __builtin_amdgcn_global_load_lds((as1_uint*)(uintptr_t)g, (as3_uint*)(uintptr_t)l,
                                   16, 0, 0);
}

// -------- fp32 -> bf16 elementwise convert, all 4 inputs in ONE dispatch --------
__global__ void cvt_all(const float* __restrict__ x, const float* __restrict__ qp,
                        const float* __restrict__ kp, const float* __restrict__ vp,
                        unsigned short* __restrict__ xb, unsigned short* __restrict__ qpb,
                        unsigned short* __restrict__ kpb, unsigned short* __restrict__ vpb) {
  const int b = blockIdx.x;
  const float* in;
  unsigned short* out;
  int base;
  if (b < 4096)      { in = x;  out = xb;  base = b; }
  else if (b < 8192) { in = qp; out = qpb; base = b - 4096; }
  else if (b < 9216) { in = kp; out = kpb; base = b - 8192; }
  else               { in = vp; out = vpb; base = b - 9216; }
  const int i = base * 256 + threadIdx.x;
  float4 v = ((const float4*)in)[i];
  u16x4 o;
  o[0] = f2bf(v.x); o[1] = f2bf(v.y); o[2] = f2bf(v.z); o[3] = f2bf(v.w);
  ((u16x4*)out)[i] = o;
}

// ------------- fp32 [R][C] -> bf16 [C][R] tiled transpose-convert --------------
__global__ __launch_bounds__(256)
void transpose_cvt(const float* __restrict__ in, unsigned short* __restrict__ out,
                   int R, int C) {
  __shared__ unsigned short t[64][72];
  const int ti = blockIdx.y * 64;
  const int tj = blockIdx.x * 64;
  const int r  = threadIdx.x >> 4;
  const int c4 = (threadIdx.x & 15) * 4;
#pragma unroll
  for (int i = 0; i < 4; ++i) {
    int row = r + i * 16;
    float4 v = *(const float4*)&in[(size_t)(ti + row) * C + tj + c4];
    t[row][c4]     = f2bf(v.x);
    t[row][c4 + 1] = f2bf(v.y);
    t[row][c4 + 2] = f2bf(v.z);
    t[row][c4 + 3] = f2bf(v.w);
  }
  __syncthreads();
#pragma unroll
  for (int i = 0; i < 4; ++i) {
    int orow = r + i * 16;  // column index j of input
    u16x4 o;
    o[0] = t[c4][orow]; o[1] = t[c4 + 1][orow];
    o[2] = t[c4 + 2][orow]; o[3] = t[c4 + 3][orow];
    *(u16x4*)&out[(size_t)(tj + orow) * R + ti + c4] = o;
  }
}

// ---------------- NT GEMM body: C[M][N] = A[M][K] * B[N][K]^T, bf16 MFMA --------
template <int BN, bool OUT_BF16>
__device__ __forceinline__
void gemm_body(const unsigned short* __restrict__ A,
               const unsigned short* __restrict__ B,
               void* __restrict__ Cout, int N, int K, float alpha,
               int bx, int by, unsigned short* lA, unsigned short* lB) {
  constexpr int NF  = BN / 32;   // 16-col fragments per wave
  constexpr int ASZ = 64 * 64;
  constexpr int BSZ = BN * 64;
  const int tid  = threadIdx.x;
  const int lane = tid & 63;
  const int w    = tid >> 6;
  const int wr   = (w >> 1) * 32;
  const int wc   = (w & 1) * (BN / 2);
  const long brow = (long)by * 64;
  const long bcol = (long)bx * BN;
  const int lr = lane & 15;
  const int lq = lane >> 4;

  const int row0 = tid >> 3;
  const int lc0  = (tid & 7) ^ (row0 & 7);

  f32x4 acc[2][NF] = {};

  const unsigned short* gA = A + (brow + row0) * (long)K + lc0 * 8;
  const unsigned short* gB = B + (bcol + row0) * (long)K + lc0 * 8;

#define G_STAGE(buf, k0)                                                          \
  {                                                                               \
    gload_lds16(gA + (k0),           lA + (buf) * ASZ + tid * 8);                 \
    gload_lds16(gA + 32l * K + (k0), lA + (buf) * ASZ + 2048 + tid * 8);          \
    _Pragma("unroll")                                                             \
    for (int g = 0; g < NF; ++g)                                                  \
      gload_lds16(gB + g * 32l * K + (k0), lB + (buf) * BSZ + g * 2048 + tid * 8);\
  }

  G_STAGE(0, 0);
  __syncthreads();

  for (int k0 = 0; k0 < K; k0 += 64) {
    const int cur = (k0 >> 6) & 1;
    if (k0 + 64 < K) G_STAGE(cur ^ 1, k0 + 64);  // prefetch rides through compute
#pragma unroll
    for (int kk = 0; kk < 2; ++kk) {
      const int j = kk * 4 + lq;
      const int ra0 = wr + lr, ra1 = wr + 16 + lr;
      bf16x8 a0 = *(const bf16x8*)&lA[cur * ASZ + ra0 * 64 + ((j ^ (ra0 & 7)) << 3)];
      bf16x8 a1 = *(const bf16x8*)&lA[cur * ASZ + ra1 * 64 + ((j ^ (ra1 & 7)) << 3)];
      bf16x8 b[NF];
#pragma unroll
      for (int n = 0; n < NF; ++n) {
        const int rb = wc + n * 16 + lr;
        b[n] = *(const bf16x8*)&lB[cur * BSZ + rb * 64 + ((j ^ (rb & 7)) << 3)];
      }
#pragma unroll
      for (int n = 0; n < NF; ++n) {
        acc[0][n] = __builtin_amdgcn_mfma_f32_16x16x32_bf16(a0, b[n], acc[0][n], 0, 0, 0);
        acc[1][n] = __builtin_amdgcn_mfma_f32_16x16x32_bf16(a1, b[n], acc[1][n], 0, 0, 0);
      }
    }
    __syncthreads();
  }
#undef G_STAGE

  const int orow = (int)brow + wr + lq * 4;
  const int ocol = (int)bcol + wc + lr;
#pragma unroll
  for (int m = 0; m < 2; ++m)
#pragma unroll
    for (int n = 0; n < NF; ++n)
#pragma unroll
      for (int r = 0; r < 4; ++r) {
        size_t row = (size_t)(orow + m * 16 + r);
        size_t col = (size_t)(ocol + n * 16);
        float v = acc[m][n][r] * alpha;
        if (OUT_BF16)
          ((unsigned short*)Cout)[row * N + col] = f2bf(v);
        else
          ((float*)Cout)[row * N + col] = v;
      }
}

template <int BN, bool OUT_BF16>
__global__ __launch_bounds__(256)
void gemm_nt(const unsigned short* __restrict__ A,
             const unsigned short* __restrict__ B,
             void* __restrict__ Cout, int N, int K, float alpha) {
  __shared__ unsigned short lA[2 * 64 * 64];
  __shared__ unsigned short lB[2 * BN * 64];
  gemm_body<BN, OUT_BF16>(A, B, Cout, N, K, alpha, blockIdx.x, blockIdx.y, lA, lB);
}

// Fused Q+K+V projections, one dispatch, flat 768-block decode (all BN=128):
//   [0,512)   Q = xb @ qpb^T (alpha=log2e/8), 16x * 32y
//   [512,640) K = xb @ kpb^T,                  4x * 32y
//   [640,768) Vt = vpb @ xb^T,                16x *  8y
__global__ __launch_bounds__(256)
void gemm_proj(const unsigned short* __restrict__ xb,
               const unsigned short* __restrict__ qpb,
               const unsigned short* __restrict__ kpb,
               const unsigned short* __restrict__ vpb,
               unsigned short* __restrict__ Qb, unsigned short* __restrict__ Kbf,
               unsigned short* __restrict__ Vtb) {
  __shared__ unsigned short lA[2 * 64 * 64];
  __shared__ unsigned short lB[2 * 128 * 64];
  const int bid = blockIdx.x;
  const unsigned short *A, *B;
  unsigned short* C;
  int N, bx, by;
  float alpha;
  if (bid < 512) {
    A = xb;  B = qpb; C = Qb;  N = 2048; alpha = 0.125f * 1.44269504088896f;
    bx = bid & 15; by = bid >> 4;
  } else if (bid < 640) {
    int b = bid - 512;
    A = xb;  B = kpb; C = Kbf; N = 512;  alpha = 1.0f;
    bx = b & 3; by = b >> 2;
  } else {
    int b = bid - 640;
    A = vpb; B = xb;  C = Vtb; N = 2048; alpha = 1.0f;
    bx = b & 15; by = b >> 4;
  }
  gemm_body<128, true>(A, B, C, N, 2048, alpha, bx, by, lA, lB);
}

// ---------------- causal GQA flash attention ----------------
// R13 restructure for OCCUPANCY: unpaired grid (32 heads, 32 q-tiles), one
// q-tile per block, LDS cut to 40960 B (2-buf K/V + unpadded XOR-swizzled P)
// -> 4 blocks/CU = 16 waves/CU (was 2 blocks / 8 waves). Sync structure =
// R8's PROVEN 2-buffer __syncthreads form (3-buf counted-vmcnt was neutral).
// qi(y) bijection {b,15-b,16+b,31-b}[y>>3] balances the 4 blocks a CU hosts.
// x = head keeps XCD pinning (R12's FETCH win).
__global__ __launch_bounds__(256, 4)
void attn64(const unsigned short* __restrict__ Q,
            const unsigned short* __restrict__ Kb,
            const unsigned short* __restrict__ Vt,
            unsigned short* __restrict__ ctx) {
  constexpr int T = 2048, DQ = 2048, DKV = 512, DH = 64;
  const int h    = blockIdx.x;
  const int hkv  = h >> 2;
  const int ya   = blockIdx.y >> 3;
  const int yb   = blockIdx.y & 7;
  const int qi   = (ya == 0) ? yb : (ya == 1) ? 15 - yb : (ya == 2) ? 16 + yb : 31 - yb;
  const int tid  = threadIdx.x;
  const int lane = tid & 63;
  const int w    = tid >> 6;
  const int lr   = lane & 15;
  const int lq   = lane >> 4;   // 0..3
  const int lk   = lq * 8;
  const int sw   = lr & 7;      // row-derived swizzle key for fragment reads

  __shared__ unsigned short lK[2][64 * 64];
  __shared__ unsigned short lV[2][64 * 64];
  __shared__ unsigned short P[4][16][64];   // unpadded; XOR-swizzled chunks

  const int row0 = tid >> 3;
  const int lc0  = (tid & 7) ^ (row0 & 7);

  // ones B-fragment for the row-sum MFMA: out-col 0 (lr==0 lanes) = 1.0 over all k
  bf16x8 ones_frag;
#pragma unroll
  for (int i = 0; i < 8; ++i) ones_frag[i] = (lr == 0) ? (__bf16)1.0f : (__bf16)0.0f;

#define STAGE_KV(bufidx, kv0)                                                        \
  {                                                                                  \
    gload_lds16(Kb + (size_t)((kv0) + row0) * DKV + hkv * DH + lc0 * 8,              \
                &lK[bufidx][tid * 8]);                                               \
    gload_lds16(Kb + (size_t)((kv0) + row0 + 32) * DKV + hkv * DH + lc0 * 8,         \
                &lK[bufidx][2048 + tid * 8]);                                        \
    gload_lds16(Vt + (size_t)(hkv * DH + row0) * T + (kv0) + lc0 * 8,                \
                &lV[bufidx][tid * 8]);                                               \
    gload_lds16(Vt + (size_t)(hkv * DH + row0 + 32) * T + (kv0) + lc0 * 8,           \
                &lV[bufidx][2048 + tid * 8]);                                        \
  }

  const int q0b = qi * 64;
  const int qw  = q0b + w * 16;

  bf16x8 qf0 = *(const bf16x8*)&Q[(size_t)(qw + lr) * DQ + h * DH + lk];
  bf16x8 qf1 = *(const bf16x8*)&Q[(size_t)(qw + lr) * DQ + h * DH + 32 + lk];

  f32x4 oacc[4] = {};
  f32x4 lacc = {};
  float mr[4];
#pragma unroll
  for (int r = 0; r < 4; ++r) mr[r] = -3.0e38f;

  const int nt = qi + 1;
  STAGE_KV(0, 0);
  __syncthreads();  // drains vmcnt(0): buf0 ready

  for (int t = 0; t < nt; ++t) {
    const int kv0 = t * 64;
    const int cur = t & 1;
    if (t + 1 < nt) STAGE_KV(cur ^ 1, kv0 + 64);  // prefetch rides through compute

    // ---- QK^T from LDS (swizzled reads); logits in log2 domain ----
    f32x4 s[4];
    __builtin_amdgcn_s_setprio(1);
#pragma unroll
    for (int n = 0; n < 4; ++n) {
      const int krow = n * 16 + lr;
      bf16x8 kf0 = *(const bf16x8*)&lK[cur][krow * 64 + ((lq ^ sw) << 3)];
      bf16x8 kf1 = *(const bf16x8*)&lK[cur][krow * 64 + (((4 + lq) ^ sw) << 3)];
      f32x4 acc = {};
      acc = __builtin_amdgcn_mfma_f32_16x16x32_bf16(qf0, kf0, acc, 0, 0, 0);
      acc = __builtin_amdgcn_mfma_f32_16x16x32_bf16(qf1, kf1, acc, 0, 0, 0);
      s[n] = acc;
    }
    __builtin_amdgcn_s_setprio(0);

    // ---- causal mask: only the diagonal tile needs it ----
    if (t == qi) {
      const int qr0 = qw + (lq << 2);
#pragma unroll
      for (int n = 0; n < 4; ++n) {
        int kc = kv0 + n * 16 + lr;
#pragma unroll
        for (int r = 0; r < 4; ++r)
          if (kc > qr0 + r) s[n][r] = -3.0e38f;
      }
    }

    // ---- online softmax with defer-max (THR = 8 log2-units) ----
    float lml[4];
#pragma unroll
    for (int r = 0; r < 4; ++r)
      lml[r] = fmaxf(fmaxf(s[0][r], s[1][r]), fmaxf(s[2][r], s[3][r]));
    const bool defer = __all((lml[0] <= mr[0] + 8.f) & (lml[1] <= mr[1] + 8.f) &
                             (lml[2] <= mr[2] + 8.f) & (lml[3] <= mr[3] + 8.f));
    if (!defer) {
#pragma unroll
      for (int r = 0; r < 4; ++r) {
        float ml = lml[r];
        ml = fmaxf(ml, __shfl_xor(ml, 1));
        ml = fmaxf(ml, __shfl_xor(ml, 2));
        ml = fmaxf(ml, __shfl_xor(ml, 4));
        ml = fmaxf(ml, __shfl_xor(ml, 8));
        float mnew = fmaxf(mr[r], ml);
        float sc   = __builtin_amdgcn_exp2f(mr[r] - mnew);
        mr[r] = mnew;
        lacc[r] *= sc;
        oacc[0][r] *= sc; oacc[1][r] *= sc;
        oacc[2][r] *= sc; oacc[3][r] *= sc;
      }
    }

    // ---- P = exp2(s - mr) (bounded by 2^8 under defer) ----
#pragma unroll
    for (int n = 0; n < 4; ++n)
#pragma unroll
      for (int r = 0; r < 4; ++r)
        s[n][r] = __builtin_amdgcn_exp2f(s[n][r] - mr[r]);

    // ---- P (C-layout) -> LDS, truncating bf16, XOR-swizzled chunks ----
    // write (row = 4lq+r, col = 16n+lr): chunk (2n + lr>>3) ^ (row&7), elem lr&7
#pragma unroll
    for (int n = 0; n < 4; ++n)
#pragma unroll
      for (int r = 0; r < 4; ++r) {
        const int prow = (lq << 2) + r;
        P[w][prow][(((2 * n + (lr >> 3)) ^ (prow & 7)) << 3) + (lr & 7)] =
            (unsigned short)(__float_as_uint(s[n][r]) >> 16);
      }
    asm volatile("s_waitcnt lgkmcnt(0)" ::: "memory");
    __builtin_amdgcn_sched_barrier(0);  // rule #18: keep PV reads below the waitcnt

    // ---- PV + row-sum (ones-MFMA) from LDS (swizzled P & V reads) ----
    __builtin_amdgcn_s_setprio(1);
#pragma unroll
    for (int ks = 0; ks < 2; ++ks) {
      bf16x8 pf = *(const bf16x8*)&P[w][lr][((ks * 4 + lq) ^ sw) << 3];
      lacc = __builtin_amdgcn_mfma_f32_16x16x32_bf16(pf, ones_frag, lacc, 0, 0, 0);
#pragma unroll
      for (int n = 0; n < 4; ++n) {
        const int vrow = n * 16 + lr;
        bf16x8 vf = *(const bf16x8*)&lV[cur][vrow * 64 + (((ks * 4 + lq) ^ sw) << 3)];
        oacc[n] = __builtin_amdgcn_mfma_f32_16x16x32_bf16(pf, vf, oacc[n], 0, 0, 0);
      }
    }
    __builtin_amdgcn_s_setprio(0);

    // one barrier per tile: prefetch landed + all waves done with buf[cur]
    __syncthreads();
  }

  float inv[4];
#pragma unroll
  for (int r = 0; r < 4; ++r) {
    float l = __shfl(lacc[r], lane & 48);  // col 0 of own row-group (lr==0 lane)
    inv[r] = 1.f / l;
  }
#pragma unroll
  for (int n = 0; n < 4; ++n)
#pragma unroll
    for (int r = 0; r < 4; ++r) {
      int qrow = qw + (lq << 2) + r;
      ctx[(size_t)qrow * DQ + h * DH + n * 16 + lr] = f2bf(oacc[n][r] * inv[r]);
    }
#undef STAGE_KV
}

extern "C" void kernel_launch(void* const* d_in, const int* in_sizes, int n_in,
                              void* d_out, int out_size, void* d_ws, size_t ws_size,
                              hipStream_t stream) {
  const float* x  = (const float*)d_in[0];
  const float* qp = (const float*)d_in[1];
  const float* kp = (const float*)d_in[2];
  const float* vp = (const float*)d_in[3];
  const float* op = (const float*)d_in[4];

  char* ws = (char*)d_ws;
  const size_t MB = 1024 * 1024;
  unsigned short* xb   = (unsigned short*)(ws + 0 * MB);   // [2048][2048]
  unsigned short* qpb  = (unsigned short*)(ws + 8 * MB);   // [2048][2048]
  unsigned short* kpb  = (unsigned short*)(ws + 16 * MB);  // [512][2048]
  unsigned short* vpb  = (unsigned short*)(ws + 18 * MB);  // [512][2048]
  unsigned short* opT  = (unsigned short*)(ws + 20 * MB);  // [2048][2048] = o_proj^T
  unsigned short* Qb   = (unsigned short*)(ws + 28 * MB);  // [2048][2048]
  unsigned short* Kbf  = (unsigned short*)(ws + 36 * MB);  // [2048][512]
  unsigned short* Vtb  = (unsigned short*)(ws + 38 * MB);  // [512][2048]
  unsigned short* ctxb = (unsigned short*)(ws + 40 * MB);  // [2048][2048]

  // fp32 -> bf16, single dispatch for all four inputs
  cvt_all<<<10240, 256, 0, stream>>>(x, qp, kp, vp, xb, qpb, kpb, vpb);
  transpose_cvt<<<dim3(32, 32), 256, 0, stream>>>(op, opT, 2048, 2048);

  // Fused Q+K+V projections (Q scaled by log2(e)/8 -> log2-domain logits)
  gemm_proj<<<768, 256, 0, stream>>>(xb, qpb, kpb, vpb, Qb, Kbf, Vtb);

  // causal GQA attention: x = head (XCD-pinned K/V), y -> balanced qi bijection
  attn64<<<dim3(32, 32), 256, 0, stream>>>(Qb, Kbf, Vtb, ctxb);

  // out = ctx @ o_proj  (via opT, NT form), fp32 epilogue to d_out
  gemm_nt<128, false><<<dim3(16, 32), 256, 0, stream>>>(ctxb, opT, d_out, 2048, 2048, 1.0f);
}